// Round 1
// 824.111 us; speedup vs baseline: 1.1657x; 1.1657x over previous
//
#include <hip/hip_runtime.h>

// Problem constants (fixed by setup_inputs): b=2, s=2048, d_model=2048,
// h=16, dh=128, past=2048, total=4096, M=b*s=4096.
#define DM    2048
#define PAST  2048
#define TOT   4096
#define SCALE 0.08838834764831845f  // 1/sqrt(128)

typedef __attribute__((ext_vector_type(8))) short bf16x8;  // 8 bf16 = 4 VGPRs
typedef __attribute__((ext_vector_type(4))) float f32x4;

typedef __attribute__((address_space(1))) void gvoid;
typedef __attribute__((address_space(3))) void lvoid;

// async global->LDS, 16B per lane. LDS dest is wave-uniform base + lane*16;
// global src is per-lane (so swizzles go on the SOURCE address, rule #21).
__device__ __forceinline__ void gload16(const void* g, void* l) {
  __builtin_amdgcn_global_load_lds((gvoid*)g, (lvoid*)l, 16, 0, 0);
}

__device__ __forceinline__ short f2b(float f) {
  unsigned u = __float_as_uint(f);
  u += 0x7fffu + ((u >> 16) & 1u);   // RNE
  return (short)(u >> 16);
}

// Load 8 consecutive elements starting at element index eidx, as bf16x8.
// F=true: source is float32 (convert, RNE). F=false: source is bf16.
template <bool F>
__device__ __forceinline__ bf16x8 ld8(const void* base, size_t eidx) {
  if constexpr (F) {
    const float* p = (const float*)base + eidx;
    float4 a = *(const float4*)p;
    float4 b = *(const float4*)(p + 4);
    bf16x8 r;
    r[0] = f2b(a.x); r[1] = f2b(a.y); r[2] = f2b(a.z); r[3] = f2b(a.w);
    r[4] = f2b(b.x); r[5] = f2b(b.y); r[6] = f2b(b.z); r[7] = f2b(b.w);
    return r;
  } else {
    return *(const bf16x8*)((const short*)base + eidx);
  }
}

template <bool F>
__device__ __forceinline__ void st1(void* base, size_t eidx, float v) {
  if constexpr (F) ((float*)base)[eidx] = v;
  else             ((short*)base)[eidx] = f2b(v);
}

// ---------------------------------------------------------------------------
// Dtype detector (unchanged): flag=1 -> fp32 inputs, flag=0 -> bf16 inputs.
// ---------------------------------------------------------------------------
__global__ void detect_dtype(const unsigned short* __restrict__ w, int* flag) {
  int cnt = 0;
#pragma unroll
  for (int i = 0; i < 4; ++i) {
    unsigned short v = w[i * 64 + threadIdx.x];
    int e = (v >> 7) & 0xFF;
    cnt += (e >= 126) ? 1 : 0;
  }
  for (int off = 32; off; off >>= 1) cnt += __shfl_down(cnt, off);
  if (threadIdx.x == 0) *flag = (cnt >= 8) ? 1 : 0;
}

// ---------------------------------------------------------------------------
// fp32 -> bf16 one-shot convert of x and the four weights (variant 1 only),
// so every GEMM can use global_load_lds on bf16.
// grid (2048,1,6): z=0,1 -> halves of x; z=2..5 -> Wq,Wk,Wv,Wo.
// ---------------------------------------------------------------------------
__global__ __launch_bounds__(256)
void to_bf16(const int* __restrict__ flag,
             const float* __restrict__ x,
             const float* __restrict__ wq, const float* __restrict__ wk,
             const float* __restrict__ wv, const float* __restrict__ wo,
             short* __restrict__ xb, short* __restrict__ wqb,
             short* __restrict__ wkb, short* __restrict__ wvb,
             short* __restrict__ wob) {
  if (*flag != 1) return;
  const float* src; short* dst; size_t off = 0;
  switch (blockIdx.z) {
    case 0: src = x;  dst = xb;  break;
    case 1: src = x;  dst = xb;  off = 4194304; break;
    case 2: src = wq; dst = wqb; break;
    case 3: src = wk; dst = wkb; break;
    case 4: src = wv; dst = wvb; break;
    default: src = wo; dst = wob; break;
  }
  const size_t i = off + ((size_t)blockIdx.x * 256 + threadIdx.x) * 8;
  *(bf16x8*)(dst + i) = ld8<true>(src, i);
}

// ---------------------------------------------------------------------------
// GEMM: C = A(4096x2048) @ W(2048x2048)^T, bf16-only inputs, m97 structure:
// 128x128 tile, BK=64, 4 waves (2x2 of 64x64), global_load_lds width=16,
// LINEAR LDS [128][64] shorts with T2 XOR swizzle applied via pre-swizzled
// global SOURCE address (chunk c stored at physical chunk c ^ (row&7)) and
// the matching XOR on the ds_read side. MODE/OF as before; MODE 1 folds
// SCALE into Q so attn skips the per-element multiply.
// ---------------------------------------------------------------------------
template <int MODE, bool OF>
__global__ __launch_bounds__(256, 2)
void gemm_bt(const int* __restrict__ flag, int want,
             const short* __restrict__ A, const short* __restrict__ W,
             void* __restrict__ dst) {
  if (*flag != want) return;
  __shared__ __align__(16) short shA[128 * 64];
  __shared__ __align__(16) short shB[128 * 64];

  const int tid  = threadIdx.x;
  const int lane = tid & 63, wid = tid >> 6;
  const int ln = lane & 15, qd = lane >> 4;
  const int wr = wid >> 1, wc = wid & 1;
  const int bm = blockIdx.y, bn = blockIdx.x;

  // staging: wave w, call i covers LDS rows 8*(4w+i)..+7 (1 KiB each);
  // lane l -> row offset l>>3, physical chunk l&7. Source chunk is
  // (l&7)^(l>>3) so reads can XOR-deswizzle by (row&7).
  const int srow = lane >> 3;
  const int scol = ((lane & 7) ^ (lane >> 3)) * 8;  // shorts (pre-swizzled src)

  const f32x4 fz = {0.f, 0.f, 0.f, 0.f};
  f32x4 acc[4][4];
#pragma unroll
  for (int i = 0; i < 4; ++i)
#pragma unroll
    for (int j = 0; j < 4; ++j) acc[i][j] = fz;

  const short* Ab = A + (size_t)bm * 128 * DM;
  const short* Wb = W + (size_t)bn * 128 * DM;

  for (int k0 = 0; k0 < DM; k0 += 64) {
#pragma unroll
    for (int i = 0; i < 4; ++i) {
      const int r8 = (wid * 4 + i) * 8 + srow;
      gload16(Ab + (size_t)r8 * DM + k0 + scol, (char*)shA + (wid * 4 + i) * 1024);
      gload16(Wb + (size_t)r8 * DM + k0 + scol, (char*)shB + (wid * 4 + i) * 1024);
    }
    __syncthreads();  // compiler drains vmcnt(0) here -> LDS tiles ready

#pragma unroll
    for (int t = 0; t < 2; ++t) {
      bf16x8 af[4], bw[4];
#pragma unroll
      for (int i = 0; i < 4; ++i) {
        const int rowA = wr * 64 + i * 16 + ln;
        const int rowB = wc * 64 + i * 16 + ln;
        const int cb   = ((t << 2) + qd) << 4;  // logical chunk byte offset
        af[i] = *(const bf16x8*)((const char*)shA + rowA * 128 + (cb ^ ((rowA & 7) << 4)));
        bw[i] = *(const bf16x8*)((const char*)shB + rowB * 128 + (cb ^ ((rowB & 7) << 4)));
      }
#pragma unroll
      for (int i = 0; i < 4; ++i)
#pragma unroll
        for (int j = 0; j < 4; ++j)
          acc[i][j] = __builtin_amdgcn_mfma_f32_16x16x32_bf16(af[i], bw[j], acc[i][j], 0, 0, 0);
    }
    __syncthreads();
  }

  // Epilogue. C/D layout: col = lane&15, row = (lane>>4)*4 + reg  [m89]
#pragma unroll
  for (int i = 0; i < 4; ++i) {
    const int rbase = bm * 128 + wr * 64 + i * 16 + qd * 4;
#pragma unroll
    for (int j = 0; j < 4; ++j) {
      const int col = bn * 128 + wc * 64 + j * 16 + ln;
#pragma unroll
      for (int r = 0; r < 4; ++r) {
        const int rr = rbase + r;
        size_t idx;
        if (MODE == 0) {
          idx = (size_t)rr * DM + col;
        } else {
          const int bb = rr >> 11, sq = rr & 2047;
          const int hh = col >> 7, dd = col & 127;
          if (MODE == 1) idx = (((size_t)bb * 16 + hh) * 2048 + sq) * 128 + dd;
          else           idx = (((size_t)bb * 16 + hh) * (size_t)TOT + PAST + sq) * 128 + dd;
        }
        float v = acc[i][j][r];
        if constexpr (MODE == 1) v *= SCALE;  // fold 1/sqrt(dh) into Q
        st1<OF>(dst, idx, v);
      }
    }
  }
}

// ---------------------------------------------------------------------------
// Copy past_k/past_v (32,2048,128) into K/V rows [0,2048). Same dtype in/out.
// ---------------------------------------------------------------------------
template <bool F>
__global__ __launch_bounds__(256)
void copy_past(const int* __restrict__ flag, int want,
               const void* __restrict__ pk, const void* __restrict__ pv,
               void* __restrict__ Kout, void* __restrict__ Vout) {
  if (*flag != want) return;
  const void* src = blockIdx.z ? pv : pk;
  void* dst = blockIdx.z ? Vout : Kout;
  const size_t c = (size_t)blockIdx.x * 256 + threadIdx.x;
  const size_t bh = c >> 15;
  const size_t rem = c & 32767;
  const size_t si = c * 8, di = bh * (size_t)TOT * 128 + rem * 8;
  if constexpr (F) {
    const float* s = (const float*)src + si;
    float* d = (float*)dst + di;
    float4 a = *(const float4*)s, b = *(const float4*)(s + 4);
    *(float4*)d = a; *(float4*)(d + 4) = b;
  } else {
    *(bf16x8*)((short*)dst + di) = *(const bf16x8*)((const short*)src + si);
  }
}

// ---------------------------------------------------------------------------
// Transpose V (32,4096,128) -> Vt bf16 (32,128,4096). Block: 64 keys x 128 dh.
// ---------------------------------------------------------------------------
template <bool F>
__global__ __launch_bounds__(256)
void transpose_v(const int* __restrict__ flag, int want,
                 const void* __restrict__ V, short* __restrict__ Vt) {
  if (*flag != want) return;
  __shared__ __align__(16) short sh[64 * 136];
  const int tid = threadIdx.x;
  const int bh = blockIdx.y, kb = blockIdx.x << 6;
  const int krow = tid >> 4, dc = tid & 15;
#pragma unroll
  for (int rnd = 0; rnd < 4; ++rnd) {
    const int key = rnd * 16 + krow;
    bf16x8 v = ld8<F>(V, ((size_t)bh * TOT + kb + key) * 128 + dc * 8);
    *(bf16x8*)(sh + key * 136 + dc * 8) = v;
  }
  __syncthreads();
  short* dstb = Vt + (size_t)bh * 128 * TOT + kb;
  const int drow = tid >> 3, keyc = tid & 7;
#pragma unroll
  for (int rnd = 0; rnd < 4; ++rnd) {
    const int dr = rnd * 32 + drow;
    bf16x8 ov;
#pragma unroll
    for (int e = 0; e < 8; ++e) ov[e] = sh[(keyc * 8 + e) * 136 + dr];
    *(bf16x8*)(dstb + (size_t)dr * TOT + keyc * 8) = ov;
  }
}

// ---------------------------------------------------------------------------
// Flash attention. Block = 64 q-rows of one bh; 4 waves x 16 rows.
// Changes vs prior: (a) XCD-bijective block swizzle so all 32 q-blocks of a
// bh land on one XCD (K fp32 2MB + Vt 1MB fit its 4MB L2); (b) T14 prefetch:
// next K/V tile's global loads issue right after the first barrier and fly
// under QK+softmax+PV; (c) mid-loop barrier removed (shP[wid] is wave-
// private, DS ops in-order per wave); (d) defer-rescale with threshold 0
// (bit-exact: skip O/l rescale when no new row max); (e) causal mask only on
// the last tile (all earlier tiles are provably unmasked); (f) SCALE folded
// into Q at GEMM time.
// ---------------------------------------------------------------------------
template <bool F>
__global__ __launch_bounds__(256, 2)
void attn_kernel(const int* __restrict__ flag, int want,
                 const short* __restrict__ Q,   // (32,2048,128) bf16, pre-scaled
                 const void* __restrict__ K,    // (32,4096,128) out dtype
                 const short* __restrict__ Vt,  // (32,128,4096) bf16
                 short* __restrict__ attn) {    // (2,2048,2048) bf16
  if (*flag != want) return;
  __shared__ __align__(16) short shK[64 * 136];
  __shared__ __align__(16) short shV[128 * 72];
  __shared__ __align__(16) short shP[4][16 * 72];

  const int tid = threadIdx.x;
  const int lane = tid & 63, wid = tid >> 6;
  const int ln = lane & 15, qd = lane >> 4;

  // XCD swizzle: linear id l -> (qt, bh) such that all 32 blocks of a bh
  // share l%8 (the XCD); bijective on the 32x32 grid.
  const int l = blockIdx.y * 32 + blockIdx.x;
  const int qt = l >> 5;
  const int bh = ((l & 7) << 2) | ((l >> 3) & 3);
  const int q0 = qt << 6;
  const int r0 = q0 + wid * 16;

  // Q fragments (A-operand: m = lane&15, k = quad*8+j) held in regs
  bf16x8 qf[4];
  const short* Qb = Q + ((size_t)bh * 2048 + r0 + ln) * 128;
#pragma unroll
  for (int t = 0; t < 4; ++t) qf[t] = *(const bf16x8*)(Qb + t * 32 + qd * 8);

  const f32x4 fz = {0.f, 0.f, 0.f, 0.f};
  f32x4 O[8];
#pragma unroll
  for (int d8 = 0; d8 < 8; ++d8) O[d8] = fz;
  float m_i[4], l_i[4];
#pragma unroll
  for (int r = 0; r < 4; ++r) { m_i[r] = -1e30f; l_i[r] = 0.f; }

  const short* Vb = Vt + (size_t)bh * 128 * TOT;
  const int ntiles = 33 + qt;  // keys 0 .. 2048+q0+63 inclusive

  const int krow = tid >> 4, kcol = tid & 15;  // K staging: 16 rows/rnd
  const int vrow = tid >> 3, vcol = tid & 7;   // V staging: 32 rows/rnd

  // prologue: tile 0 into regs
  bf16x8 vk[4], vv[4];
#pragma unroll
  for (int rnd = 0; rnd < 4; ++rnd) {
    vk[rnd] = ld8<F>(K, ((size_t)bh * TOT + rnd * 16 + krow) * 128 + kcol * 8);
    vv[rnd] = *(const bf16x8*)(Vb + (size_t)(rnd * 32 + vrow) * TOT + vcol * 8);
  }

  for (int kt = 0; kt < ntiles; ++kt) {
    const int kb = kt << 6;
#pragma unroll
    for (int rnd = 0; rnd < 4; ++rnd) {
      *(bf16x8*)(shK + (rnd * 16 + krow) * 136 + kcol * 8) = vk[rnd];
      *(bf16x8*)(shV + (rnd * 32 + vrow) * 72 + vcol * 8) = vv[rnd];
    }
    __syncthreads();

    // prefetch next tile (issued AFTER the barrier so its drain can't catch
    // these; they complete under QK+softmax+PV, consumed at next loop top)
    if (kt + 1 < ntiles) {
      const int nb = kb + 64;
#pragma unroll
      for (int rnd = 0; rnd < 4; ++rnd) {
        vk[rnd] = ld8<F>(K, ((size_t)bh * TOT + nb + rnd * 16 + krow) * 128 + kcol * 8);
        vv[rnd] = *(const bf16x8*)(Vb + (size_t)(rnd * 32 + vrow) * TOT + nb + vcol * 8);
      }
    }

    // S = Q K^T   (S C-layout: row(q) = qd*4+r, col(key) = ln)
    f32x4 sacc[4];
#pragma unroll
    for (int j = 0; j < 4; ++j) sacc[j] = fz;
#pragma unroll
    for (int t = 0; t < 4; ++t) {
#pragma unroll
      for (int j = 0; j < 4; ++j) {
        bf16x8 kf = *(const bf16x8*)(shK + (j * 16 + ln) * 136 + ((t << 2) + qd) * 8);
        sacc[j] = __builtin_amdgcn_mfma_f32_16x16x32_bf16(qf[t], kf, sacc[j], 0, 0, 0);
      }
    }

    const bool lastt = (kt == ntiles - 1);  // only tile that can mask

    // online softmax per row r (Q pre-scaled; no per-element SCALE here)
#pragma unroll
    for (int r = 0; r < 4; ++r) {
      float rowm = -1e30f;
      if (lastt) {
        const int lim = PAST + r0 + qd * 4 + r;
#pragma unroll
        for (int j = 0; j < 4; ++j) {
          const int kj = kb + j * 16 + ln;
          float s = sacc[j][r];
          s = (kj <= lim) ? s : -1e30f;
          sacc[j][r] = s;
          rowm = fmaxf(rowm, s);
        }
      } else {
#pragma unroll
        for (int j = 0; j < 4; ++j) rowm = fmaxf(rowm, sacc[j][r]);
      }
      rowm = fmaxf(rowm, __shfl_xor(rowm, 1));
      rowm = fmaxf(rowm, __shfl_xor(rowm, 2));
      rowm = fmaxf(rowm, __shfl_xor(rowm, 4));
      rowm = fmaxf(rowm, __shfl_xor(rowm, 8));
      const float mold = m_i[r];
      const bool renew = rowm > mold;            // uniform within row group
      const float mnew = renew ? rowm : mold;
      float rsum = 0.f;
#pragma unroll
      for (int j = 0; j < 4; ++j) {
        const float p = __expf(sacc[j][r] - mnew);
        sacc[j][r] = p;
        rsum += p;
      }
      rsum += __shfl_xor(rsum, 1);
      rsum += __shfl_xor(rsum, 2);
      rsum += __shfl_xor(rsum, 4);
      rsum += __shfl_xor(rsum, 8);
      if (renew) {  // defer-rescale, threshold 0: exact
        const float alpha = __expf(mold - mnew);
        m_i[r] = mnew;
        l_i[r] = l_i[r] * alpha + rsum;
#pragma unroll
        for (int d8 = 0; d8 < 8; ++d8) O[d8][r] *= alpha;
      } else {
        l_i[r] += rsum;
      }
      const int rowL = qd * 4 + r;
#pragma unroll
      for (int j = 0; j < 4; ++j)
        shP[wid][rowL * 72 + j * 16 + ln] = f2b(sacc[j][r]);
    }
    // no barrier: shP[wid] is wave-private; DS ops complete in order per wave

    // O += P V   (A = P: m=ln, k=key; B = Vt rows: n=dh, k=key)
#pragma unroll
    for (int t = 0; t < 2; ++t) {
      bf16x8 pf = *(const bf16x8*)(&shP[wid][ln * 72 + ((t << 2) + qd) * 8]);
#pragma unroll
      for (int d8 = 0; d8 < 8; ++d8) {
        bf16x8 vf = *(const bf16x8*)(shV + (d8 * 16 + ln) * 72 + ((t << 2) + qd) * 8);
        O[d8] = __builtin_amdgcn_mfma_f32_16x16x32_bf16(pf, vf, O[d8], 0, 0, 0);
      }
    }
    __syncthreads();  // protect shK/shV before next tile's staging writes
  }

  // epilogue: attn layout (b, s, h*dh), bf16 workspace
  const int bb = bh >> 4, hh = bh & 15;
#pragma unroll
  for (int r = 0; r < 4; ++r) {
    const float inv = 1.0f / l_i[r];
    const int qr = r0 + qd * 4 + r;
    short* dst = attn + ((size_t)bb * 2048 + qr) * DM + hh * 128;
#pragma unroll
    for (int d8 = 0; d8 < 8; ++d8)
      dst[d8 * 16 + ln] = f2b(O[d8][r] * inv);
  }
}

// ---------------------------------------------------------------------------
extern "C" void kernel_launch(void* const* d_in, const int* in_sizes, int n_in,
                              void* d_out, int out_size, void* d_ws, size_t ws_size,
                              hipStream_t stream) {
  (void)in_sizes; (void)n_in; (void)out_size; (void)ws_size;
  const void* x  = d_in[0];
  const void* pk = d_in[1];
  const void* pv = d_in[2];
  const void* Wq = d_in[3];
  const void* Wk = d_in[4];
  const void* Wv = d_in[5];
  const void* Wo = d_in[6];

  int* flag = (int*)d_ws;
  short* base = (short*)((char*)d_ws + 256);
  // workspace layout (shorts). Aliases are lifetime-safe:
  //   xb (variant-1 bf16 x) aliases attnws: xb dead after V GEMM, attnws
  //     first written by attn_kernel (later in stream).
  //   wq/wk/wv bf16 alias Vtws: dead after their GEMMs, Vtws first written
  //     by transpose_v (later).
  short* Qws    = base;                 // 8,388,608  (32,2048,128) bf16
  short* attnws = base + 8388608;       // 8,388,608  (2,2048,2048) bf16
  short* xb     = attnws;               // alias
  short* Vtws   = base + 16777216;      // 16,777,216 (32,128,4096) bf16
  short* wqb    = Vtws;                 // alias (3 x 4,194,304 fits)
  short* wkb    = Vtws + 4194304;
  short* wvb    = Vtws + 8388608;
  short* wob    = base + 33554432;      // 4,194,304  (lives to the end)

  // bf16-output layout
  short* outB  = (short*)d_out;
  short* KoutB = outB + (size_t)8388608;
  short* VoutB = KoutB + (size_t)16777216;
  // fp32-output layout
  float* outF  = (float*)d_out;
  float* KoutF = outF + (size_t)8388608;
  float* VoutF = KoutF + (size_t)16777216;

  dim3 blk(256);
  detect_dtype<<<1, 64, 0, stream>>>((const unsigned short*)Wq, flag);

  // variant-1 prep: one-shot fp32 -> bf16 of x and weights
  to_bf16<<<dim3(2048, 1, 6), blk, 0, stream>>>(flag,
      (const float*)x, (const float*)Wq, (const float*)Wk, (const float*)Wv,
      (const float*)Wo, xb, wqb, wkb, wvb, wob);

  // ---- variant 0: inputs/outputs bf16 ----
  gemm_bt<1, false><<<dim3(16, 32), blk, 0, stream>>>(flag, 0, (const short*)x, (const short*)Wq, Qws);
  gemm_bt<2, false><<<dim3(16, 32), blk, 0, stream>>>(flag, 0, (const short*)x, (const short*)Wk, KoutB);
  gemm_bt<2, false><<<dim3(16, 32), blk, 0, stream>>>(flag, 0, (const short*)x, (const short*)Wv, VoutB);
  copy_past<false><<<dim3(4096, 1, 2), blk, 0, stream>>>(flag, 0, pk, pv, KoutB, VoutB);
  transpose_v<false><<<dim3(64, 32), blk, 0, stream>>>(flag, 0, VoutB, Vtws);
  attn_kernel<false><<<dim3(32, 32), blk, 0, stream>>>(flag, 0, Qws, KoutB, Vtws, attnws);
  gemm_bt<0, false><<<dim3(16, 32), blk, 0, stream>>>(flag, 0, attnws, (const short*)Wo, outB);

  // ---- variant 1: inputs/outputs fp32 (bf16 internals) ----
  gemm_bt<1, false><<<dim3(16, 32), blk, 0, stream>>>(flag, 1, xb, wqb, Qws);
  gemm_bt<2, true ><<<dim3(16, 32), blk, 0, stream>>>(flag, 1, xb, wkb, KoutF);
  gemm_bt<2, true ><<<dim3(16, 32), blk, 0, stream>>>(flag, 1, xb, wvb, VoutF);
  copy_past<true><<<dim3(4096, 1, 2), blk, 0, stream>>>(flag, 1, pk, pv, KoutF, VoutF);
  transpose_v<true><<<dim3(64, 32), blk, 0, stream>>>(flag, 1, VoutF, Vtws);
  attn_kernel<true><<<dim3(32, 32), blk, 0, stream>>>(flag, 1, Qws, KoutF, Vtws, attnws);
  gemm_bt<0, true ><<<dim3(16, 32), blk, 0, stream>>>(flag, 1, attnws, wob, outF);
}

// Round 2
// 639.651 us; speedup vs baseline: 1.5019x; 1.2884x over previous
//
#include <hip/hip_runtime.h>

// Problem constants (fixed by setup_inputs): b=2, s=2048, d_model=2048,
// h=16, dh=128, past=2048, total=4096, M=b*s=4096.
#define DM    2048
#define PAST  2048
#define TOT   4096
#define SCALE 0.08838834764831845f  // 1/sqrt(128)

typedef __attribute__((ext_vector_type(8))) short bf16x8;  // 8 bf16 = 4 VGPRs
typedef __attribute__((ext_vector_type(4))) float f32x4;
typedef __attribute__((ext_vector_type(4))) short s16x4;

typedef __attribute__((address_space(1))) void gvoid;
typedef __attribute__((address_space(3))) void lvoid;

// async global->LDS, 16B per lane. LDS dest is wave-uniform base + lane*16;
// global src is per-lane (so swizzles go on the SOURCE address, rule #21).
__device__ __forceinline__ void gload16(const void* g, void* l) {
  __builtin_amdgcn_global_load_lds((gvoid*)g, (lvoid*)l, 16, 0, 0);
}

__device__ __forceinline__ short f2b(float f) {
  unsigned u = __float_as_uint(f);
  u += 0x7fffu + ((u >> 16) & 1u);   // RNE
  return (short)(u >> 16);
}

__device__ __forceinline__ unsigned pk2(float a, float b) {
  return (unsigned)(unsigned short)f2b(a) | ((unsigned)(unsigned short)f2b(b) << 16);
}

// Load 8 consecutive elements starting at element index eidx, as bf16x8.
// F=true: source is float32 (convert, RNE). F=false: source is bf16.
template <bool F>
__device__ __forceinline__ bf16x8 ld8(const void* base, size_t eidx) {
  if constexpr (F) {
    const float* p = (const float*)base + eidx;
    float4 a = *(const float4*)p;
    float4 b = *(const float4*)(p + 4);
    bf16x8 r;
    r[0] = f2b(a.x); r[1] = f2b(a.y); r[2] = f2b(a.z); r[3] = f2b(a.w);
    r[4] = f2b(b.x); r[5] = f2b(b.y); r[6] = f2b(b.z); r[7] = f2b(b.w);
    return r;
  } else {
    return *(const bf16x8*)((const short*)base + eidx);
  }
}

// ---------------------------------------------------------------------------
// Dtype detector: flag=1 -> fp32 inputs, flag=0 -> bf16 inputs.
// ---------------------------------------------------------------------------
__global__ void detect_dtype(const unsigned short* __restrict__ w, int* flag) {
  int cnt = 0;
#pragma unroll
  for (int i = 0; i < 4; ++i) {
    unsigned short v = w[i * 64 + threadIdx.x];
    int e = (v >> 7) & 0xFF;
    cnt += (e >= 126) ? 1 : 0;
  }
  for (int off = 32; off; off >>= 1) cnt += __shfl_down(cnt, off);
  if (threadIdx.x == 0) *flag = (cnt >= 8) ? 1 : 0;
}

// ---------------------------------------------------------------------------
// fp32 -> bf16 one-shot convert of x and the four weights (variant 1 only).
// grid (2048,1,6): z=0,1 -> halves of x; z=2..5 -> Wq,Wk,Wv,Wo.
// ---------------------------------------------------------------------------
__global__ __launch_bounds__(256)
void to_bf16(const int* __restrict__ flag,
             const float* __restrict__ x,
             const float* __restrict__ wq, const float* __restrict__ wk,
             const float* __restrict__ wv, const float* __restrict__ wo,
             short* __restrict__ xb, short* __restrict__ wqb,
             short* __restrict__ wkb, short* __restrict__ wvb,
             short* __restrict__ wob) {
  if (*flag != 1) return;
  const float* src; short* dst; size_t off = 0;
  switch (blockIdx.z) {
    case 0: src = x;  dst = xb;  break;
    case 1: src = x;  dst = xb;  off = 4194304; break;
    case 2: src = wq; dst = wqb; break;
    case 3: src = wk; dst = wkb; break;
    case 4: src = wv; dst = wvb; break;
    default: src = wo; dst = wob; break;
  }
  const size_t i = off + ((size_t)blockIdx.x * 256 + threadIdx.x) * 8;
  *(bf16x8*)(dst + i) = ld8<true>(src, i);
}

// ---------------------------------------------------------------------------
// Shared GEMM main loop: acc += A(128 rows) @ W(128 rows)^T over K=2048.
// m97 structure: global_load_lds width=16, linear LDS [128][64] shorts with
// T2 XOR swizzle via pre-swizzled global SOURCE + XOR on ds_read.
// ---------------------------------------------------------------------------
__device__ __forceinline__ void gemm_mainloop(
    const short* __restrict__ Ab, const short* __restrict__ Wb,
    short* shA, short* shB, f32x4 acc[4][4]) {
  const int tid  = threadIdx.x;
  const int lane = tid & 63, wid = tid >> 6;
  const int ln = lane & 15, qd = lane >> 4;
  const int wr = wid >> 1, wc = wid & 1;

  const int srow = lane >> 3;
  const int scol = ((lane & 7) ^ (lane >> 3)) * 8;  // pre-swizzled src chunk

  for (int k0 = 0; k0 < DM; k0 += 64) {
#pragma unroll
    for (int i = 0; i < 4; ++i) {
      const int r8 = (wid * 4 + i) * 8 + srow;
      gload16(Ab + (size_t)r8 * DM + k0 + scol, (char*)shA + (wid * 4 + i) * 1024);
      gload16(Wb + (size_t)r8 * DM + k0 + scol, (char*)shB + (wid * 4 + i) * 1024);
    }
    __syncthreads();

#pragma unroll
    for (int t = 0; t < 2; ++t) {
      bf16x8 af[4], bw[4];
#pragma unroll
      for (int i = 0; i < 4; ++i) {
        const int rowA = wr * 64 + i * 16 + ln;
        const int rowB = wc * 64 + i * 16 + ln;
        const int cb   = ((t << 2) + qd) << 4;
        af[i] = *(const bf16x8*)((const char*)shA + rowA * 128 + (cb ^ ((rowA & 7) << 4)));
        bw[i] = *(const bf16x8*)((const char*)shB + rowB * 128 + (cb ^ ((rowB & 7) << 4)));
      }
#pragma unroll
      for (int i = 0; i < 4; ++i)
#pragma unroll
        for (int j = 0; j < 4; ++j)
          acc[i][j] = __builtin_amdgcn_mfma_f32_16x16x32_bf16(af[i], bw[j], acc[i][j], 0, 0, 0);
    }
    __syncthreads();
  }
}

// ---------------------------------------------------------------------------
// Fused QKV GEMM. grid (48, 32): bn segment 0=Q,1=K,2=V. Single launch for
// both dtype variants (flag-selected pointers). Q -> Qws bf16, pre-scaled by
// 1/sqrt(dh). K/V -> d_out rows [PAST,TOT) in the output dtype.
// ---------------------------------------------------------------------------
__global__ __launch_bounds__(256, 2)
void qkv_gemm(const int* __restrict__ flag,
              const short* __restrict__ x0, const short* __restrict__ x1,
              const short* __restrict__ wq0, const short* __restrict__ wk0,
              const short* __restrict__ wv0,
              const short* __restrict__ wq1, const short* __restrict__ wk1,
              const short* __restrict__ wv1,
              short* __restrict__ Qws,
              short* __restrict__ Kb, float* __restrict__ Kf,
              short* __restrict__ Vb, float* __restrict__ Vf) {
  __shared__ __align__(16) short shA[128 * 64];
  __shared__ __align__(16) short shB[128 * 64];
  const int isF = *flag;
  const int bm = blockIdx.y, bn = blockIdx.x;
  const int seg = bn >> 4, bnl = bn & 15;

  const short* A = isF ? x1 : x0;
  const short* W = (seg == 0) ? (isF ? wq1 : wq0)
                  : (seg == 1) ? (isF ? wk1 : wk0)
                               : (isF ? wv1 : wv0);

  const f32x4 fz = {0.f, 0.f, 0.f, 0.f};
  f32x4 acc[4][4];
#pragma unroll
  for (int i = 0; i < 4; ++i)
#pragma unroll
    for (int j = 0; j < 4; ++j) acc[i][j] = fz;

  gemm_mainloop(A + (size_t)bm * 128 * DM, W + (size_t)bnl * 128 * DM, shA, shB, acc);

  const int tid  = threadIdx.x;
  const int lane = tid & 63, wid = tid >> 6;
  const int ln = lane & 15, qd = lane >> 4;
  const int wr = wid >> 1, wc = wid & 1;

#pragma unroll
  for (int i = 0; i < 4; ++i) {
    const int rbase = bm * 128 + wr * 64 + i * 16 + qd * 4;
#pragma unroll
    for (int j = 0; j < 4; ++j) {
      const int col = bnl * 128 + wc * 64 + j * 16 + ln;
#pragma unroll
      for (int r = 0; r < 4; ++r) {
        const int rr = rbase + r;
        const int bb = rr >> 11, sq = rr & 2047;
        const int hh = col >> 7, dd = col & 127;
        float v = acc[i][j][r];
        if (seg == 0) {
          const size_t idx = (((size_t)bb * 16 + hh) * 2048 + sq) * 128 + dd;
          Qws[idx] = f2b(v * SCALE);
        } else {
          const size_t idx = (((size_t)bb * 16 + hh) * (size_t)TOT + PAST + sq) * 128 + dd;
          if (seg == 1) { if (isF) Kf[idx] = v; else Kb[idx] = f2b(v); }
          else          { if (isF) Vf[idx] = v; else Vb[idx] = f2b(v); }
        }
      }
    }
  }
}

// ---------------------------------------------------------------------------
// Output GEMM: out = attn(bf16 ws) @ Wo^T, store in output dtype (runtime).
// ---------------------------------------------------------------------------
__global__ __launch_bounds__(256, 2)
void out_gemm(const int* __restrict__ flag,
              const short* __restrict__ A,
              const short* __restrict__ wo0, const short* __restrict__ wo1,
              void* __restrict__ dst) {
  __shared__ __align__(16) short shA[128 * 64];
  __shared__ __align__(16) short shB[128 * 64];
  const int isF = *flag;
  const int bm = blockIdx.y, bn = blockIdx.x;
  const short* W = isF ? wo1 : wo0;

  const f32x4 fz = {0.f, 0.f, 0.f, 0.f};
  f32x4 acc[4][4];
#pragma unroll
  for (int i = 0; i < 4; ++i)
#pragma unroll
    for (int j = 0; j < 4; ++j) acc[i][j] = fz;

  gemm_mainloop(A + (size_t)bm * 128 * DM, W + (size_t)bn * 128 * DM, shA, shB, acc);

  const int tid  = threadIdx.x;
  const int lane = tid & 63, wid = tid >> 6;
  const int ln = lane & 15, qd = lane >> 4;
  const int wr = wid >> 1, wc = wid & 1;

#pragma unroll
  for (int i = 0; i < 4; ++i) {
    const int rbase = bm * 128 + wr * 64 + i * 16 + qd * 4;
#pragma unroll
    for (int j = 0; j < 4; ++j) {
      const int col = bn * 128 + wc * 64 + j * 16 + ln;
#pragma unroll
      for (int r = 0; r < 4; ++r) {
        const size_t idx = (size_t)(rbase + r) * DM + col;
        if (isF) ((float*)dst)[idx] = acc[i][j][r];
        else     ((short*)dst)[idx] = f2b(acc[i][j][r]);
      }
    }
  }
}

// ---------------------------------------------------------------------------
// Copy past_k/past_v (32,2048,128) into K/V rows [0,2048). Runtime dtype.
// ---------------------------------------------------------------------------
__global__ __launch_bounds__(256)
void copy_past(const int* __restrict__ flag,
               const void* __restrict__ pk, const void* __restrict__ pv,
               short* __restrict__ Kb, float* __restrict__ Kf,
               short* __restrict__ Vb, float* __restrict__ Vf) {
  const int isF = *flag;
  const void* src = blockIdx.z ? pv : pk;
  const size_t c = (size_t)blockIdx.x * 256 + threadIdx.x;
  const size_t bh = c >> 15;
  const size_t rem = c & 32767;
  const size_t si = c * 8, di = bh * (size_t)TOT * 128 + rem * 8;
  if (isF) {
    float* dst = blockIdx.z ? Vf : Kf;
    const float* s = (const float*)src + si;
    float4 a = *(const float4*)s, b = *(const float4*)(s + 4);
    *(float4*)(dst + di) = a; *(float4*)(dst + di + 4) = b;
  } else {
    short* dst = blockIdx.z ? Vb : Kb;
    *(bf16x8*)(dst + di) = *(const bf16x8*)((const short*)src + si);
  }
}

// ---------------------------------------------------------------------------
// Transpose V (32,4096,128) -> Vt bf16 (32,128,4096). Runtime src dtype.
// ---------------------------------------------------------------------------
__global__ __launch_bounds__(256)
void transpose_v(const int* __restrict__ flag,
                 const short* __restrict__ Vb, const float* __restrict__ Vf,
                 short* __restrict__ Vt) {
  __shared__ __align__(16) short sh[64 * 136];
  const int isF = *flag;
  const int tid = threadIdx.x;
  const int bh = blockIdx.y, kb = blockIdx.x << 6;
  const int krow = tid >> 4, dc = tid & 15;
#pragma unroll
  for (int rnd = 0; rnd < 4; ++rnd) {
    const int key = rnd * 16 + krow;
    const size_t idx = ((size_t)bh * TOT + kb + key) * 128 + dc * 8;
    bf16x8 v = isF ? ld8<true>(Vf, idx) : ld8<false>(Vb, idx);
    *(bf16x8*)(sh + key * 136 + dc * 8) = v;
  }
  __syncthreads();
  short* dstb = Vt + (size_t)bh * 128 * TOT + kb;
  const int drow = tid >> 3, keyc = tid & 7;
#pragma unroll
  for (int rnd = 0; rnd < 4; ++rnd) {
    const int dr = rnd * 32 + drow;
    bf16x8 ov;
#pragma unroll
    for (int e = 0; e < 8; ++e) ov[e] = sh[(keyc * 8 + e) * 136 + dr];
    *(bf16x8*)(dstb + (size_t)dr * TOT + keyc * 8) = ov;
  }
}

// ---------------------------------------------------------------------------
// Flash attention, swapped-operand form. Block = 128 q-rows of one bh;
// 4 waves x 32 rows. S = mfma(K,Q) -> S[key][q], col q = lane&15 -> each
// lane owns 2 full q-rows: softmax is in-register (15 fmax + 2 shfl), P is
// packed to LDS as 4x ds_write_b64/lane. O = mfma(Vt,P) -> O[dh][q], col
// q = lane&15 again -> rescale/l_i are lane-local. T14 prefetch; mask only
// the last two tiles; XCD-bijective swizzle keeps each bh on one XCD.
// ---------------------------------------------------------------------------
template <bool F>
__global__ __launch_bounds__(256, 2)
void attn_kernel(const int* __restrict__ flag, int want,
                 const short* __restrict__ Q,   // (32,2048,128) bf16, pre-scaled
                 const void* __restrict__ K,    // (32,4096,128) out dtype
                 const short* __restrict__ Vt,  // (32,128,4096) bf16
                 short* __restrict__ attn) {    // (2,2048,2048) bf16
  if (*flag != want) return;
  __shared__ __align__(16) short shK[64 * 136];
  __shared__ __align__(16) short shV[128 * 72];
  __shared__ __align__(16) short shP[4][32 * 72];

  const int tid = threadIdx.x;
  const int lane = tid & 63, wid = tid >> 6;
  const int ln = lane & 15, qd = lane >> 4;

  // XCD swizzle: grid (16,32) -> 512 blocks; same bh => same l%8 => same XCD.
  const int l = blockIdx.y * 16 + blockIdx.x;
  const int qt = l >> 5;                          // 0..15, 128 q-rows each
  const int bh = ((l & 7) << 2) | ((l >> 3) & 3); // bijective 5-bit map
  const int q0 = qt << 7;
  const int r0w = q0 + wid * 32;                  // this wave's 32 q-rows

  // Q fragments as B-operand: n=q=lane&15, k=qd*8+e. Two 16-row groups (mi).
  bf16x8 qf[2][4];
#pragma unroll
  for (int mi = 0; mi < 2; ++mi) {
    const short* Qb = Q + ((size_t)bh * 2048 + r0w + mi * 16 + ln) * 128;
#pragma unroll
    for (int t = 0; t < 4; ++t) qf[mi][t] = *(const bf16x8*)(Qb + t * 32 + qd * 8);
  }

  const f32x4 fz = {0.f, 0.f, 0.f, 0.f};
  f32x4 O[2][8];           // O[dh-tile][q]: elem r -> dh = dt*16+qd*4+r, col q=ln
#pragma unroll
  for (int mi = 0; mi < 2; ++mi)
#pragma unroll
    for (int dt = 0; dt < 8; ++dt) O[mi][dt] = fz;
  float m_i[2] = {-1e30f, -1e30f}, l_i[2] = {0.f, 0.f};

  const short* Vb = Vt + (size_t)bh * 128 * TOT;
  const int ntiles = 34 + 2 * qt;  // keys 0 .. 2048+q0+127 inclusive

  const int krow = tid >> 4, kcol = tid & 15;  // K staging: 16 rows/rnd
  const int vrow = tid >> 3, vcol = tid & 7;   // V staging: 32 rows/rnd
  short* shPw = &shP[wid][0];

  // prologue: tile 0 into regs
  bf16x8 vk[4], vv[4];
#pragma unroll
  for (int rnd = 0; rnd < 4; ++rnd) {
    vk[rnd] = ld8<F>(K, ((size_t)bh * TOT + rnd * 16 + krow) * 128 + kcol * 8);
    vv[rnd] = *(const bf16x8*)(Vb + (size_t)(rnd * 32 + vrow) * TOT + vcol * 8);
  }

  for (int kt = 0; kt < ntiles; ++kt) {
    const int kb = kt << 6;
#pragma unroll
    for (int rnd = 0; rnd < 4; ++rnd) {
      *(bf16x8*)(shK + (rnd * 16 + krow) * 136 + kcol * 8) = vk[rnd];
      *(bf16x8*)(shV + (rnd * 32 + vrow) * 72 + vcol * 8) = vv[rnd];
    }
    __syncthreads();

    // prefetch next tile; completes under QK+softmax+PV
    if (kt + 1 < ntiles) {
      const int nb = kb + 64;
#pragma unroll
      for (int rnd = 0; rnd < 4; ++rnd) {
        vk[rnd] = ld8<F>(K, ((size_t)bh * TOT + nb + rnd * 16 + krow) * 128 + kcol * 8);
        vv[rnd] = *(const bf16x8*)(Vb + (size_t)(rnd * 32 + vrow) * TOT + nb + vcol * 8);
      }
    }

    // S = mfma(K,Q): row = key = j*16 + qd*4 + r, col = q = mi*16 + ln
    f32x4 sacc[2][4];
#pragma unroll
    for (int mi = 0; mi < 2; ++mi)
#pragma unroll
      for (int j = 0; j < 4; ++j) sacc[mi][j] = fz;
#pragma unroll
    for (int t = 0; t < 4; ++t) {
#pragma unroll
      for (int j = 0; j < 4; ++j) {
        bf16x8 kf = *(const bf16x8*)(shK + (j * 16 + ln) * 136 + ((t << 2) + qd) * 8);
        sacc[0][j] = __builtin_amdgcn_mfma_f32_16x16x32_bf16(kf, qf[0][t], sacc[0][j], 0, 0, 0);
        sacc[1][j] = __builtin_amdgcn_mfma_f32_16x16x32_bf16(kf, qf[1][t], sacc[1][j], 0, 0, 0);
      }
    }

    const bool maskt = (kt >= ntiles - 2);  // only last two tiles can mask

    // online softmax: per lane, 2 q-rows (q = r0w + mi*16 + ln), keys in regs
#pragma unroll
    for (int mi = 0; mi < 2; ++mi) {
      const int q = r0w + mi * 16 + ln;
      float vmax = -1e30f;
      if (maskt) {
        const int lim = PAST + q;
#pragma unroll
        for (int j = 0; j < 4; ++j)
#pragma unroll
          for (int r = 0; r < 4; ++r) {
            const int kj = kb + j * 16 + qd * 4 + r;
            float s = sacc[mi][j][r];
            s = (kj <= lim) ? s : -1e30f;
            sacc[mi][j][r] = s;
            vmax = fmaxf(vmax, s);
          }
      } else {
#pragma unroll
        for (int j = 0; j < 4; ++j)
#pragma unroll
          for (int r = 0; r < 4; ++r) vmax = fmaxf(vmax, sacc[mi][j][r]);
      }
      vmax = fmaxf(vmax, __shfl_xor(vmax, 16));
      vmax = fmaxf(vmax, __shfl_xor(vmax, 32));
      const float mold = m_i[mi];
      const bool renew = vmax > mold;
      const float mnew = renew ? vmax : mold;
      float rsum = 0.f;
#pragma unroll
      for (int j = 0; j < 4; ++j)
#pragma unroll
        for (int r = 0; r < 4; ++r) {
          const float p = __expf(sacc[mi][j][r] - mnew);
          sacc[mi][j][r] = p;
          rsum += p;
        }
      rsum += __shfl_xor(rsum, 16);
      rsum += __shfl_xor(rsum, 32);
      if (renew) {  // defer-rescale, threshold 0: exact
        const float alpha = __expf(mold - mnew);
        m_i[mi] = mnew;
        l_i[mi] = l_i[mi] * alpha + rsum;
#pragma unroll
        for (int dt = 0; dt < 8; ++dt) O[mi][dt] *= alpha;
      } else {
        l_i[mi] += rsum;
      }
      // pack P row q (4 consecutive keys per j) -> shP[q-local][key-local]
      const int qr = mi * 16 + ln;
#pragma unroll
      for (int j = 0; j < 4; ++j) {
        uint2 w;
        w.x = pk2(sacc[mi][j][0], sacc[mi][j][1]);
        w.y = pk2(sacc[mi][j][2], sacc[mi][j][3]);
        *(uint2*)(shPw + qr * 72 + j * 16 + qd * 4) = w;
      }
    }
    // no barrier: shP[wid] is wave-private; DS ops complete in order per wave

    // O += mfma(Vt,P): A = Vt rows (m=dh), B = P (n=q), k = key
#pragma unroll
    for (int tk = 0; tk < 2; ++tk) {
      bf16x8 pf[2];
#pragma unroll
      for (int mi = 0; mi < 2; ++mi)
        pf[mi] = *(const bf16x8*)(shPw + (mi * 16 + ln) * 72 + ((tk << 2) + qd) * 8);
#pragma unroll
      for (int dt = 0; dt < 8; ++dt) {
        bf16x8 vf = *(const bf16x8*)(shV + (dt * 16 + ln) * 72 + ((tk << 2) + qd) * 8);
        O[0][dt] = __builtin_amdgcn_mfma_f32_16x16x32_bf16(vf, pf[0], O[0][dt], 0, 0, 0);
        O[1][dt] = __builtin_amdgcn_mfma_f32_16x16x32_bf16(vf, pf[1], O[1][dt], 0, 0, 0);
      }
    }
    __syncthreads();  // protect shK/shV before next tile's staging writes
  }

  // epilogue: O col=q=ln is lane-local; dh = dt*16 + qd*4 + r (4 consecutive)
  const int bb = bh >> 4, hh = bh & 15;
#pragma unroll
  for (int mi = 0; mi < 2; ++mi) {
    const float inv = 1.0f / l_i[mi];
    const int q = r0w + mi * 16 + ln;
    short* dst = attn + ((size_t)bb * 2048 + q) * DM + hh * 128;
#pragma unroll
    for (int dt = 0; dt < 8; ++dt) {
      s16x4 o;
#pragma unroll
      for (int r = 0; r < 4; ++r) o[r] = f2b(O[mi][dt][r] * inv);
      *(s16x4*)(dst + dt * 16 + qd * 4) = o;
    }
  }
}

// ---------------------------------------------------------------------------
extern "C" void kernel_launch(void* const* d_in, const int* in_sizes, int n_in,
                              void* d_out, int out_size, void* d_ws, size_t ws_size,
                              hipStream_t stream) {
  (void)in_sizes; (void)n_in; (void)out_size; (void)ws_size;
  const void* x  = d_in[0];
  const void* pk = d_in[1];
  const void* pv = d_in[2];
  const void* Wq = d_in[3];
  const void* Wk = d_in[4];
  const void* Wv = d_in[5];
  const void* Wo = d_in[6];

  int* flag = (int*)d_ws;
  short* base = (short*)((char*)d_ws + 256);
  // workspace layout (shorts). Aliases are lifetime-safe:
  //   xb aliases attnws (xb dead after QKV GEMM; attnws written by attn later)
  //   wq/wk/wvb alias Vtws (dead after QKV GEMM; Vtws written by transpose_v)
  short* Qws    = base;                 // 8,388,608  (32,2048,128) bf16
  short* attnws = base + 8388608;       // 8,388,608  (2,2048,2048) bf16
  short* xb     = attnws;               // alias
  short* Vtws   = base + 16777216;      // 16,777,216 (32,128,4096) bf16
  short* wqb    = Vtws;                 // alias (3 x 4,194,304 fits)
  short* wkb    = Vtws + 4194304;
  short* wvb    = Vtws + 8388608;
  short* wob    = base + 33554432;      // 4,194,304  (lives to the end)

  // bf16-output layout
  short* outB  = (short*)d_out;
  short* KoutB = outB + (size_t)8388608;
  short* VoutB = KoutB + (size_t)16777216;
  // fp32-output layout
  float* outF  = (float*)d_out;
  float* KoutF = outF + (size_t)8388608;
  float* VoutF = KoutF + (size_t)16777216;

  dim3 blk(256);
  detect_dtype<<<1, 64, 0, stream>>>((const unsigned short*)Wq, flag);

  to_bf16<<<dim3(2048, 1, 6), blk, 0, stream>>>(flag,
      (const float*)x, (const float*)Wq, (const float*)Wk, (const float*)Wv,
      (const float*)Wo, xb, wqb, wkb, wvb, wob);

  qkv_gemm<<<dim3(48, 32), blk, 0, stream>>>(flag,
      (const short*)x, xb,
      (const short*)Wq, (const short*)Wk, (const short*)Wv,
      wqb, wkb, wvb,
      Qws, KoutB, KoutF, VoutB, VoutF);

  copy_past<<<dim3(4096, 1, 2), blk, 0, stream>>>(flag, pk, pv,
      KoutB, KoutF, VoutB, VoutF);

  transpose_v<<<dim3(64, 32), blk, 0, stream>>>(flag, VoutB, VoutF, Vtws);

  attn_kernel<false><<<dim3(16, 32), blk, 0, stream>>>(flag, 0, Qws, KoutB, Vtws, attnws);
  attn_kernel<true ><<<dim3(16, 32), blk, 0, stream>>>(flag, 1, Qws, KoutF, Vtws, attnws);

  out_gemm<<<dim3(16, 32), blk, 0, stream>>>(flag, attnws, (const short*)Wo, wob, d_out);
}